// Round 5
// baseline (1796.181 us; speedup 1.0000x reference)
//
#include <hip/hip_runtime.h>
#include <hip/hip_cooperative_groups.h>

namespace cg = cooperative_groups;

#define MROWS   16384
#define NCOLS   256
#define NV4     (NCOLS / 4)        // 64 float4 per row
#define CHUNKS  8                  // column chunks: col>>11 -> 2048 rows = 2 MB each
#define CSHIFT  11
#define NB      (MROWS * CHUNKS)   // 131072 buckets

// chunk-major key: all rows of one chunk contiguous in pack
__device__ __forceinline__ int mk_key(int r, int c) {
    return ((c >> CSHIFT) << 14) | r;
}

#define SPMM_BLOCKS 2048                       // 8 blocks/CU, grid-sync'd phases
#define RPB (MROWS / SPMM_BLOCKS)              // 8 rows per block
#define RPW (RPB / 4)                          // 2 rows per wave

#define SCAT_BLOCKS 2048

// ---------------- K2: histogram of chunk-major keys ----------------
__global__ void k_hist(const int* __restrict__ rows, const int* __restrict__ cols,
                       int* __restrict__ cnt, int nnz) {
    int t = blockIdx.x * blockDim.x + threadIdx.x;
    if (t < nnz) atomicAdd(&cnt[mk_key(rows[t], cols[t])], 1);
}

// ---------------- scan stage 1: coalesced per-block sums (512 x 256) ----------------
__global__ __launch_bounds__(256) void k_scan1(const int* __restrict__ cnt,
                                               int* __restrict__ bsum) {
    __shared__ int sm[256];
    const int t = threadIdx.x;
    sm[t] = cnt[blockIdx.x * 256 + t];
    __syncthreads();
    for (int off = 128; off > 0; off >>= 1) {
        if (t < off) sm[t] += sm[t + off];
        __syncthreads();
    }
    if (t == 0) bsum[blockIdx.x] = sm[0];
}

// ---------------- scan stage 2: 1 block scans the 512 block sums ----------------
__global__ __launch_bounds__(512) void k_scan2(const int* __restrict__ bsum,
                                               int* __restrict__ bpre) {
    __shared__ int sm[512];
    const int t = threadIdx.x;
    int v = bsum[t];
    sm[t] = v;
    __syncthreads();
    for (int off = 1; off < 512; off <<= 1) {
        int u = 0;
        if (t >= off) u = sm[t - off];
        __syncthreads();
        if (t >= off) sm[t] += u;
        __syncthreads();
    }
    bpre[t] = sm[t] - v;                 // exclusive
    if (t == 511) bpre[512] = sm[511];   // total
}

// ---------------- scan stage 3: coalesced final exclusive prefix ----------------
__global__ __launch_bounds__(256) void k_scan3(const int* __restrict__ cnt_in,
                                               const int* __restrict__ bpre,
                                               int* __restrict__ bstart,
                                               int* __restrict__ cursor) {
    __shared__ int sm[256];
    const int t = threadIdx.x;
    const int g = blockIdx.x * 256 + t;
    int v = cnt_in[g];
    sm[t] = v;
    __syncthreads();
    for (int off = 1; off < 256; off <<= 1) {
        int u = 0;
        if (t >= off) u = sm[t - off];
        __syncthreads();
        if (t >= off) sm[t] += u;
        __syncthreads();
    }
    int excl = sm[t] - v + bpre[blockIdx.x];
    bstart[g] = excl;
    cursor[g] = excl;
    if (blockIdx.x == gridDim.x - 1 && t == 255) bstart[NB] = bpre[512];
}

// ---------------- K4: XCD-filtered scatter ----------------
// Blocks with the same (blockIdx&7) land on the same XCD (round-robin
// heuristic); each handles only nnz whose column-chunk == that filter, so all
// pack stores from one XCD target one contiguous ~1 MB region that stays in
// its L2 and evicts once. Correctness does not depend on the mapping.
__global__ __launch_bounds__(256) void k_scatter(const float* __restrict__ values,
                                                 const int* __restrict__ rows,
                                                 const int* __restrict__ cols,
                                                 int* __restrict__ cursor,
                                                 int2* __restrict__ pack, int nnz) {
    const int f      = blockIdx.x & 7;          // chunk filter
    const int slice  = blockIdx.x >> 3;         // 256 slices
    const int nslice = SCAT_BLOCKS / 8;
    const int per    = (nnz + nslice - 1) / nslice;
    const int begin  = slice * per;
    const int end    = min(begin + per, nnz);
    for (int i = begin + threadIdx.x; i < end; i += 256) {
        int c = cols[i];
        if ((c >> CSHIFT) == f) {
            int r   = rows[i];
            int pos = atomicAdd(&cursor[mk_key(r, c)], 1);
            pack[pos] = make_int2(c, __float_as_int(values[i]));
        }
    }
}

// ---------------- K5: grid-synced chunk-phased gather-accumulate ----------------
// SYNC=true: launched cooperatively, grid.sync() between chunk phases makes
// phase lockstep exact -> per-XCD working set is one 2 MB dense slice.
// SYNC=false: identical math, no barrier (fallback if coop launch fails).
template <bool SYNC>
__global__ __launch_bounds__(256, 8) void k_spmm_t(const float4* __restrict__ in4,
                                                   const int2* __restrict__ pack,
                                                   const int* __restrict__ bstart,
                                                   const float4* __restrict__ dense4,
                                                   float4* __restrict__ out4) {
    const int wave = threadIdx.x >> 6;
    const int lane = threadIdx.x & 63;
    const int rb   = blockIdx.x * RPB + wave * RPW;   // rows rb, rb+1
    const int ph0  = blockIdx.x & 7;

    float4 a0 = make_float4(0.f, 0.f, 0.f, 0.f);
    float4 a1 = make_float4(0.f, 0.f, 0.f, 0.f);

    for (int p = 0; p < CHUNKS; ++p) {
        const int c    = (ph0 + p) & 7;
        const int base = c * MROWS + rb;
        int s  = bstart[base];
        int e0 = bstart[base + 1];
        int e  = bstart[base + 2];
        s  = __builtin_amdgcn_readfirstlane(s);
        e0 = __builtin_amdgcn_readfirstlane(e0);
        e  = __builtin_amdgcn_readfirstlane(e);

        int i = s;
        for (; i + 4 <= e; i += 4) {
            int2 q0 = pack[i + 0], q1 = pack[i + 1];
            int2 q2 = pack[i + 2], q3 = pack[i + 3];
            float4 d0 = dense4[q0.x * NV4 + lane];
            float4 d1 = dense4[q1.x * NV4 + lane];
            float4 d2 = dense4[q2.x * NV4 + lane];
            float4 d3 = dense4[q3.x * NV4 + lane];
            float v0 = __int_as_float(q0.y), v1 = __int_as_float(q1.y);
            float v2 = __int_as_float(q2.y), v3 = __int_as_float(q3.y);
            if (i + 3 < e0) {            // whole batch -> row0 (uniform branch)
                a0.x += v0 * d0.x; a0.y += v0 * d0.y; a0.z += v0 * d0.z; a0.w += v0 * d0.w;
                a0.x += v1 * d1.x; a0.y += v1 * d1.y; a0.z += v1 * d1.z; a0.w += v1 * d1.w;
                a0.x += v2 * d2.x; a0.y += v2 * d2.y; a0.z += v2 * d2.z; a0.w += v2 * d2.w;
                a0.x += v3 * d3.x; a0.y += v3 * d3.y; a0.z += v3 * d3.z; a0.w += v3 * d3.w;
            } else if (i >= e0) {        // whole batch -> row1
                a1.x += v0 * d0.x; a1.y += v0 * d0.y; a1.z += v0 * d0.z; a1.w += v0 * d0.w;
                a1.x += v1 * d1.x; a1.y += v1 * d1.y; a1.z += v1 * d1.z; a1.w += v1 * d1.w;
                a1.x += v2 * d2.x; a1.y += v2 * d2.y; a1.z += v2 * d2.z; a1.w += v2 * d2.w;
                a1.x += v3 * d3.x; a1.y += v3 * d3.y; a1.z += v3 * d3.z; a1.w += v3 * d3.w;
            } else {                     // boundary batch: mask-route (<=1 per phase)
                float w00 = (i + 0 < e0) ? v0 : 0.f, w10 = v0 - w00;
                float w01 = (i + 1 < e0) ? v1 : 0.f, w11 = v1 - w01;
                float w02 = (i + 2 < e0) ? v2 : 0.f, w12 = v2 - w02;
                float w03 = (i + 3 < e0) ? v3 : 0.f, w13 = v3 - w03;
                a0.x += w00 * d0.x; a0.y += w00 * d0.y; a0.z += w00 * d0.z; a0.w += w00 * d0.w;
                a1.x += w10 * d0.x; a1.y += w10 * d0.y; a1.z += w10 * d0.z; a1.w += w10 * d0.w;
                a0.x += w01 * d1.x; a0.y += w01 * d1.y; a0.z += w01 * d1.z; a0.w += w01 * d1.w;
                a1.x += w11 * d1.x; a1.y += w11 * d1.y; a1.z += w11 * d1.z; a1.w += w11 * d1.w;
                a0.x += w02 * d2.x; a0.y += w02 * d2.y; a0.z += w02 * d2.z; a0.w += w02 * d2.w;
                a1.x += w12 * d2.x; a1.y += w12 * d2.y; a1.z += w12 * d2.z; a1.w += w12 * d2.w;
                a0.x += w03 * d3.x; a0.y += w03 * d3.y; a0.z += w03 * d3.z; a0.w += w03 * d3.w;
                a1.x += w13 * d3.x; a1.y += w13 * d3.y; a1.z += w13 * d3.z; a1.w += w13 * d3.w;
            }
        }
        for (; i < e; ++i) {
            int2 q   = pack[i];
            float4 d = dense4[q.x * NV4 + lane];
            float v  = __int_as_float(q.y);
            if (i < e0) {
                a0.x += v * d.x; a0.y += v * d.y; a0.z += v * d.z; a0.w += v * d.w;
            } else {
                a1.x += v * d.x; a1.y += v * d.y; a1.z += v * d.z; a1.w += v * d.w;
            }
        }

        if (SYNC && p + 1 < CHUNKS) cg::this_grid().sync();
    }

    int o = rb * NV4 + lane;
    float4 iv = in4[o];
    out4[o] = make_float4(iv.x + a0.x, iv.y + a0.y, iv.z + a0.z, iv.w + a0.w);
    o += NV4;
    iv = in4[o];
    out4[o] = make_float4(iv.x + a1.x, iv.y + a1.y, iv.z + a1.z, iv.w + a1.w);
}

// ---------------- Fallback path (if ws too small): copy + atomic scatter ----------------
__global__ void k_copy4(const float4* __restrict__ in4, float4* __restrict__ out4, int n4) {
    int t = blockIdx.x * blockDim.x + threadIdx.x;
    if (t < n4) out4[t] = in4[t];
}

__global__ void k_atomic(const float* __restrict__ values, const int* __restrict__ rows,
                         const int* __restrict__ cols, const float4* __restrict__ dense4,
                         float* __restrict__ out, int nnz) {
    long long t = (long long)blockIdx.x * blockDim.x + threadIdx.x;
    long long total = (long long)nnz * 64;
    if (t >= total) return;
    int i   = (int)(t >> 6);
    int seg = (int)(t & 63);
    float v  = values[i];
    float4 d = dense4[cols[i] * NV4 + seg];
    float* o = out + (size_t)rows[i] * NCOLS + seg * 4;
    atomicAdd(o + 0, v * d.x);
    atomicAdd(o + 1, v * d.y);
    atomicAdd(o + 2, v * d.z);
    atomicAdd(o + 3, v * d.w);
}

extern "C" void kernel_launch(void* const* d_in, const int* in_sizes, int n_in,
                              void* d_out, int out_size, void* d_ws, size_t ws_size,
                              hipStream_t stream) {
    const float* input_mat = (const float*)d_in[0];
    const float* values    = (const float*)d_in[1];
    const int*   rows      = (const int*)d_in[2];
    const int*   cols      = (const int*)d_in[3];
    const float* dense     = (const float*)d_in[4];
    float*       out       = (float*)d_out;

    const int nnz = in_sizes[1];

    // ws layout: cursor[NB] | bstart[NB+1] | bsum[512] | bpre[513] | pack[nnz] int2
    const size_t off_cursor = 0;
    const size_t off_bs     = (size_t)NB * 4;
    const size_t off_bsum   = off_bs + ((size_t)NB + 1) * 4;
    const size_t off_bpre   = off_bsum + 512 * 4;
    size_t off_pack         = off_bpre + 513 * 4;
    off_pack                = (off_pack + 255) & ~(size_t)255;
    const size_t need       = off_pack + (size_t)nnz * 8;

    char* ws = (char*)d_ws;

    if (ws_size >= need) {
        int*  cursor = (int*)(ws + off_cursor);
        int*  bstart = (int*)(ws + off_bs);
        int*  bsum   = (int*)(ws + off_bsum);
        int*  bpre   = (int*)(ws + off_bpre);
        int2* pack   = (int2*)(ws + off_pack);

        hipMemsetAsync(cursor, 0, (size_t)NB * 4, stream);
        k_hist<<<(nnz + 255) / 256, 256, 0, stream>>>(rows, cols, cursor, nnz);
        k_scan1<<<NB / 256, 256, 0, stream>>>(cursor, bsum);
        k_scan2<<<1, 512, 0, stream>>>(bsum, bpre);
        k_scan3<<<NB / 256, 256, 0, stream>>>(cursor, bpre, bstart, cursor);
        k_scatter<<<SCAT_BLOCKS, 256, 0, stream>>>(values, rows, cols, cursor,
                                                   pack, nnz);

        const float4* in4p  = (const float4*)input_mat;
        const int2*   packp = pack;
        const int*    bsp   = bstart;
        const float4* d4p   = (const float4*)dense;
        float4*       o4p   = (float4*)out;
        void* kargs[] = {(void*)&in4p, (void*)&packp, (void*)&bsp,
                         (void*)&d4p, (void*)&o4p};
        hipError_t e = hipLaunchCooperativeKernel(
            (const void*)(k_spmm_t<true>), dim3(SPMM_BLOCKS), dim3(256),
            kargs, 0, stream);
        if (e != hipSuccess) {
            // non-cooperative fallback: same math, statistical locality only
            k_spmm_t<false><<<SPMM_BLOCKS, 256, 0, stream>>>(in4p, packp, bsp,
                                                             d4p, o4p);
        }
    } else {
        // fallback: atomic scatter (slow but needs no scratch)
        const int n4 = MROWS * NV4;
        k_copy4<<<(n4 + 255) / 256, 256, 0, stream>>>((const float4*)input_mat,
                                                      (float4*)out, n4);
        long long total = (long long)nnz * 64;
        int blocks = (int)((total + 255) / 256);
        k_atomic<<<blocks, 256, 0, stream>>>(values, rows, cols, (const float4*)dense,
                                             out, nnz);
    }
}

// Round 6
// 179.783 us; speedup vs baseline: 9.9908x; 9.9908x over previous
//
#include <hip/hip_runtime.h>

#define MROWS   16384
#define NCOLS   256
#define NV4     (NCOLS / 4)        // 64 float4 per row
#define CHUNKS  8                  // column chunks: col>>11 -> 2048 rows = 2 MB each
#define CSHIFT  11
#define NB      (MROWS * CHUNKS)   // 131072 buckets

// chunk-major key: all rows of one chunk contiguous in pack
__device__ __forceinline__ int mk_key(int r, int c) {
    return ((c >> CSHIFT) << 14) | r;
}

// 1024 blocks x 512 threads: 4 blocks/CU (R3's proven lockstep granularity,
// identical per-block work) but 32 waves/CU -> full occupancy to hide L2
// gather latency. 8 waves/block, 2 rows/wave.
#define SPMM_BLOCKS 1024
#define RPB (MROWS / SPMM_BLOCKS)              // 16 rows per block
#define RPW (RPB / 8)                          // 2 rows per wave

#define SCAT_BLOCKS 2048

// ---------------- K2: histogram of chunk-major keys ----------------
__global__ void k_hist(const int* __restrict__ rows, const int* __restrict__ cols,
                       int* __restrict__ cnt, int nnz) {
    int t = blockIdx.x * blockDim.x + threadIdx.x;
    if (t < nnz) atomicAdd(&cnt[mk_key(rows[t], cols[t])], 1);
}

// ---------------- scan stage 1: coalesced per-block sums (512 x 256) ----------------
__global__ __launch_bounds__(256) void k_scan1(const int* __restrict__ cnt,
                                               int* __restrict__ bsum) {
    __shared__ int sm[256];
    const int t = threadIdx.x;
    sm[t] = cnt[blockIdx.x * 256 + t];
    __syncthreads();
    for (int off = 128; off > 0; off >>= 1) {
        if (t < off) sm[t] += sm[t + off];
        __syncthreads();
    }
    if (t == 0) bsum[blockIdx.x] = sm[0];
}

// ---------------- scan stage 2: 1 block scans the 512 block sums ----------------
__global__ __launch_bounds__(512) void k_scan2(const int* __restrict__ bsum,
                                               int* __restrict__ bpre) {
    __shared__ int sm[512];
    const int t = threadIdx.x;
    int v = bsum[t];
    sm[t] = v;
    __syncthreads();
    for (int off = 1; off < 512; off <<= 1) {
        int u = 0;
        if (t >= off) u = sm[t - off];
        __syncthreads();
        if (t >= off) sm[t] += u;
        __syncthreads();
    }
    bpre[t] = sm[t] - v;                 // exclusive
    if (t == 511) bpre[512] = sm[511];   // total
}

// ---------------- scan stage 3: coalesced final exclusive prefix ----------------
__global__ __launch_bounds__(256) void k_scan3(const int* __restrict__ cnt_in,
                                               const int* __restrict__ bpre,
                                               int* __restrict__ bstart,
                                               int* __restrict__ cursor) {
    __shared__ int sm[256];
    const int t = threadIdx.x;
    const int g = blockIdx.x * 256 + t;
    int v = cnt_in[g];
    sm[t] = v;
    __syncthreads();
    for (int off = 1; off < 256; off <<= 1) {
        int u = 0;
        if (t >= off) u = sm[t - off];
        __syncthreads();
        if (t >= off) sm[t] += u;
        __syncthreads();
    }
    int excl = sm[t] - v + bpre[blockIdx.x];
    bstart[g] = excl;
    cursor[g] = excl;
    if (blockIdx.x == gridDim.x - 1 && t == 255) bstart[NB] = bpre[512];
}

// ---------------- K4: XCD-filtered scatter ----------------
// Blocks with the same (blockIdx&7) land on the same XCD (round-robin
// heuristic); each handles only nnz whose column-chunk == that filter, so all
// pack stores from one XCD target one contiguous ~1 MB region that stays in
// its L2 and evicts once. Correctness does not depend on the mapping.
__global__ __launch_bounds__(256) void k_scatter(const float* __restrict__ values,
                                                 const int* __restrict__ rows,
                                                 const int* __restrict__ cols,
                                                 int* __restrict__ cursor,
                                                 int2* __restrict__ pack, int nnz) {
    const int f      = blockIdx.x & 7;          // chunk filter
    const int slice  = blockIdx.x >> 3;         // 256 slices
    const int nslice = SCAT_BLOCKS / 8;
    const int per    = (nnz + nslice - 1) / nslice;
    const int begin  = slice * per;
    const int end    = min(begin + per, nnz);
    for (int i = begin + threadIdx.x; i < end; i += 256) {
        int c = cols[i];
        if ((c >> CSHIFT) == f) {
            int r   = rows[i];
            int pos = atomicAdd(&cursor[mk_key(r, c)], 1);
            pack[pos] = make_int2(c, __float_as_int(values[i]));
        }
    }
}

// ---------------- K5: chunk-phased gather-accumulate, full occupancy ----------------
// Statistical lockstep: 1024 equal-work blocks, all co-resident, started
// together -> blocks traverse column chunks in near-phase; blockIdx&7 staggers
// the starting chunk per XCD so each XCD's L2 holds one ~2 MB slice at a time.
__global__ __launch_bounds__(512, 8) void k_spmm(const float4* __restrict__ in4,
                                                 const int2* __restrict__ pack,
                                                 const int* __restrict__ bstart,
                                                 const float4* __restrict__ dense4,
                                                 float4* __restrict__ out4) {
    const int wave = threadIdx.x >> 6;          // 0..7
    const int lane = threadIdx.x & 63;
    const int rb   = blockIdx.x * RPB + wave * RPW;   // rows rb, rb+1
    const int ph0  = blockIdx.x & 7;

    float4 a0 = make_float4(0.f, 0.f, 0.f, 0.f);
    float4 a1 = make_float4(0.f, 0.f, 0.f, 0.f);

    for (int p = 0; p < CHUNKS; ++p) {
        const int c    = (ph0 + p) & 7;
        const int base = c * MROWS + rb;
        int s  = bstart[base];
        int e0 = bstart[base + 1];
        int e  = bstart[base + 2];
        s  = __builtin_amdgcn_readfirstlane(s);
        e0 = __builtin_amdgcn_readfirstlane(e0);
        e  = __builtin_amdgcn_readfirstlane(e);

        int i = s;
        for (; i + 4 <= e; i += 4) {
            int2 q0 = pack[i + 0], q1 = pack[i + 1];
            int2 q2 = pack[i + 2], q3 = pack[i + 3];
            float4 d0 = dense4[q0.x * NV4 + lane];
            float4 d1 = dense4[q1.x * NV4 + lane];
            float4 d2 = dense4[q2.x * NV4 + lane];
            float4 d3 = dense4[q3.x * NV4 + lane];
            float v0 = __int_as_float(q0.y), v1 = __int_as_float(q1.y);
            float v2 = __int_as_float(q2.y), v3 = __int_as_float(q3.y);
            if (i + 3 < e0) {            // whole batch -> row0 (uniform branch)
                a0.x += v0 * d0.x; a0.y += v0 * d0.y; a0.z += v0 * d0.z; a0.w += v0 * d0.w;
                a0.x += v1 * d1.x; a0.y += v1 * d1.y; a0.z += v1 * d1.z; a0.w += v1 * d1.w;
                a0.x += v2 * d2.x; a0.y += v2 * d2.y; a0.z += v2 * d2.z; a0.w += v2 * d2.w;
                a0.x += v3 * d3.x; a0.y += v3 * d3.y; a0.z += v3 * d3.z; a0.w += v3 * d3.w;
            } else if (i >= e0) {        // whole batch -> row1
                a1.x += v0 * d0.x; a1.y += v0 * d0.y; a1.z += v0 * d0.z; a1.w += v0 * d0.w;
                a1.x += v1 * d1.x; a1.y += v1 * d1.y; a1.z += v1 * d1.z; a1.w += v1 * d1.w;
                a1.x += v2 * d2.x; a1.y += v2 * d2.y; a1.z += v2 * d2.z; a1.w += v2 * d2.w;
                a1.x += v3 * d3.x; a1.y += v3 * d3.y; a1.z += v3 * d3.z; a1.w += v3 * d3.w;
            } else {                     // boundary batch: mask-route (<=1 per phase)
                float w00 = (i + 0 < e0) ? v0 : 0.f, w10 = v0 - w00;
                float w01 = (i + 1 < e0) ? v1 : 0.f, w11 = v1 - w01;
                float w02 = (i + 2 < e0) ? v2 : 0.f, w12 = v2 - w02;
                float w03 = (i + 3 < e0) ? v3 : 0.f, w13 = v3 - w03;
                a0.x += w00 * d0.x; a0.y += w00 * d0.y; a0.z += w00 * d0.z; a0.w += w00 * d0.w;
                a1.x += w10 * d0.x; a1.y += w10 * d0.y; a1.z += w10 * d0.z; a1.w += w10 * d0.w;
                a0.x += w01 * d1.x; a0.y += w01 * d1.y; a0.z += w01 * d1.z; a0.w += w01 * d1.w;
                a1.x += w11 * d1.x; a1.y += w11 * d1.y; a1.z += w11 * d1.z; a1.w += w11 * d1.w;
                a0.x += w02 * d2.x; a0.y += w02 * d2.y; a0.z += w02 * d2.z; a0.w += w02 * d2.w;
                a1.x += w12 * d2.x; a1.y += w12 * d2.y; a1.z += w12 * d2.z; a1.w += w12 * d2.w;
                a0.x += w03 * d3.x; a0.y += w03 * d3.y; a0.z += w03 * d3.z; a0.w += w03 * d3.w;
                a1.x += w13 * d3.x; a1.y += w13 * d3.y; a1.z += w13 * d3.z; a1.w += w13 * d3.w;
            }
        }
        for (; i < e; ++i) {
            int2 q   = pack[i];
            float4 d = dense4[q.x * NV4 + lane];
            float v  = __int_as_float(q.y);
            if (i < e0) {
                a0.x += v * d.x; a0.y += v * d.y; a0.z += v * d.z; a0.w += v * d.w;
            } else {
                a1.x += v * d.x; a1.y += v * d.y; a1.z += v * d.z; a1.w += v * d.w;
            }
        }
    }

    int o = rb * NV4 + lane;
    float4 iv = in4[o];
    out4[o] = make_float4(iv.x + a0.x, iv.y + a0.y, iv.z + a0.z, iv.w + a0.w);
    o += NV4;
    iv = in4[o];
    out4[o] = make_float4(iv.x + a1.x, iv.y + a1.y, iv.z + a1.z, iv.w + a1.w);
}

// ---------------- Fallback path (if ws too small): copy + atomic scatter ----------------
__global__ void k_copy4(const float4* __restrict__ in4, float4* __restrict__ out4, int n4) {
    int t = blockIdx.x * blockDim.x + threadIdx.x;
    if (t < n4) out4[t] = in4[t];
}

__global__ void k_atomic(const float* __restrict__ values, const int* __restrict__ rows,
                         const int* __restrict__ cols, const float4* __restrict__ dense4,
                         float* __restrict__ out, int nnz) {
    long long t = (long long)blockIdx.x * blockDim.x + threadIdx.x;
    long long total = (long long)nnz * 64;
    if (t >= total) return;
    int i   = (int)(t >> 6);
    int seg = (int)(t & 63);
    float v  = values[i];
    float4 d = dense4[cols[i] * NV4 + seg];
    float* o = out + (size_t)rows[i] * NCOLS + seg * 4;
    atomicAdd(o + 0, v * d.x);
    atomicAdd(o + 1, v * d.y);
    atomicAdd(o + 2, v * d.z);
    atomicAdd(o + 3, v * d.w);
}

extern "C" void kernel_launch(void* const* d_in, const int* in_sizes, int n_in,
                              void* d_out, int out_size, void* d_ws, size_t ws_size,
                              hipStream_t stream) {
    const float* input_mat = (const float*)d_in[0];
    const float* values    = (const float*)d_in[1];
    const int*   rows      = (const int*)d_in[2];
    const int*   cols      = (const int*)d_in[3];
    const float* dense     = (const float*)d_in[4];
    float*       out       = (float*)d_out;

    const int nnz = in_sizes[1];

    // ws layout: cursor[NB] | bstart[NB+1] | bsum[512] | bpre[513] | pack[nnz] int2
    const size_t off_cursor = 0;
    const size_t off_bs     = (size_t)NB * 4;
    const size_t off_bsum   = off_bs + ((size_t)NB + 1) * 4;
    const size_t off_bpre   = off_bsum + 512 * 4;
    size_t off_pack         = off_bpre + 513 * 4;
    off_pack                = (off_pack + 255) & ~(size_t)255;
    const size_t need       = off_pack + (size_t)nnz * 8;

    char* ws = (char*)d_ws;

    if (ws_size >= need) {
        int*  cursor = (int*)(ws + off_cursor);
        int*  bstart = (int*)(ws + off_bs);
        int*  bsum   = (int*)(ws + off_bsum);
        int*  bpre   = (int*)(ws + off_bpre);
        int2* pack   = (int2*)(ws + off_pack);

        hipMemsetAsync(cursor, 0, (size_t)NB * 4, stream);
        k_hist<<<(nnz + 255) / 256, 256, 0, stream>>>(rows, cols, cursor, nnz);
        k_scan1<<<NB / 256, 256, 0, stream>>>(cursor, bsum);
        k_scan2<<<1, 512, 0, stream>>>(bsum, bpre);
        k_scan3<<<NB / 256, 256, 0, stream>>>(cursor, bpre, bstart, cursor);
        k_scatter<<<SCAT_BLOCKS, 256, 0, stream>>>(values, rows, cols, cursor,
                                                   pack, nnz);
        k_spmm<<<SPMM_BLOCKS, 512, 0, stream>>>((const float4*)input_mat, pack, bstart,
                                                (const float4*)dense, (float4*)out);
    } else {
        // fallback: atomic scatter (slow but needs no scratch)
        const int n4 = MROWS * NV4;
        k_copy4<<<(n4 + 255) / 256, 256, 0, stream>>>((const float4*)input_mat,
                                                      (float4*)out, n4);
        long long total = (long long)nnz * 64;
        int blocks = (int)((total + 255) / 256);
        k_atomic<<<blocks, 256, 0, stream>>>(values, rows, cols, (const float4*)dense,
                                             out, nnz);
    }
}